// Round 2
// baseline (305497.949 us; speedup 1.0000x reference)
//
#include <hip/hip_runtime.h>
#include <stdint.h>
#include <math.h>

#define HD 1024
#define BB 8
#define LL 2048
#define NBLK 256
#define NTHR 512

typedef unsigned short u16;
typedef unsigned int u32;

using bf16x8 = __attribute__((ext_vector_type(8))) short;
using f32x4  = __attribute__((ext_vector_type(4))) float;

__device__ __forceinline__ u16 f2bf(float f) {
  u32 x = __float_as_uint(f);
  x += 0x7fffu + ((x >> 16) & 1u);
  return (u16)(x >> 16);
}
__device__ __forceinline__ float bf2f(u16 u) {
  return __uint_as_float(((u32)u) << 16);
}
__device__ __forceinline__ float dot4(float4 a, float4 b) {
  return fmaf(a.x, b.x, fmaf(a.y, b.y, fmaf(a.z, b.z, a.w * b.w)));
}

// ---------------- input LN: x [16384,1024] f32 -> xn bf16 ----------------
__global__ __launch_bounds__(256) void k_ln_x(const float* __restrict__ x,
    const float* __restrict__ g, const float* __restrict__ b,
    u16* __restrict__ xn) {
  int row = blockIdx.x;
  int t = threadIdx.x;
  const float4* xr = (const float4*)(x + (size_t)row * HD);
  float4 v = xr[t];
  float s = v.x + v.y + v.z + v.w;
  float ss = v.x * v.x + v.y * v.y + v.z * v.z + v.w * v.w;
#pragma unroll
  for (int off = 32; off; off >>= 1) { s += __shfl_down(s, off); ss += __shfl_down(ss, off); }
  __shared__ float red[8];
  if ((t & 63) == 0) { red[t >> 6] = s; red[4 + (t >> 6)] = ss; }
  __syncthreads();
  s = red[0] + red[1] + red[2] + red[3];
  ss = red[4] + red[5] + red[6] + red[7];
  float m = s * (1.0f / HD);
  float rstd = rsqrtf(ss * (1.0f / HD) - m * m + 1e-5f);
  float4 gv = ((const float4*)g)[t];
  float4 bv = ((const float4*)b)[t];
  ushort4 o;
  o.x = f2bf((v.x - m) * rstd * gv.x + bv.x);
  o.y = f2bf((v.y - m) * rstd * gv.y + bv.y);
  o.z = f2bf((v.z - m) * rstd * gv.z + bv.z);
  o.w = f2bf((v.w - m) * rstd * gv.w + bv.w);
  *(ushort4*)(xn + (size_t)row * HD + t * 4) = o;
}

// ---------------- output LN, in place on f32 rows ----------------
__global__ __launch_bounds__(256) void k_out_ln(float* __restrict__ y,
    const float* __restrict__ g, const float* __restrict__ b) {
  int row = blockIdx.x;
  int t = threadIdx.x;
  float4* yr = (float4*)(y + (size_t)row * HD);
  float4 v = yr[t];
  float s = v.x + v.y + v.z + v.w;
  float ss = v.x * v.x + v.y * v.y + v.z * v.z + v.w * v.w;
#pragma unroll
  for (int off = 32; off; off >>= 1) { s += __shfl_down(s, off); ss += __shfl_down(ss, off); }
  __shared__ float red[8];
  if ((t & 63) == 0) { red[t >> 6] = s; red[4 + (t >> 6)] = ss; }
  __syncthreads();
  s = red[0] + red[1] + red[2] + red[3];
  ss = red[4] + red[5] + red[6] + red[7];
  float m = s * (1.0f / HD);
  float rstd = rsqrtf(ss * (1.0f / HD) - m * m + 1e-5f);
  float4 gv = ((const float4*)g)[t];
  float4 bv = ((const float4*)b)[t];
  float4 o;
  o.x = (v.x - m) * rstd * gv.x + bv.x;
  o.y = (v.y - m) * rstd * gv.y + bv.y;
  o.z = (v.z - m) * rstd * gv.z + bv.z;
  o.w = (v.w - m) * rstd * gv.w + bv.w;
  yr[t] = o;
}

// ---------------- pack input-side weights to bf16: win=[3][1024][1024] ----
__global__ __launch_bounds__(256) void k_pack_win(const float* __restrict__ wz,
    const float* __restrict__ wr, const float* __restrict__ wh,
    u16* __restrict__ win) {
  int gid = blockIdx.x;           // 0..3071
  int gate = gid >> 10, o = gid & 1023;
  const float* w = (gate == 0) ? wz : ((gate == 1) ? wr : wh);
  const float* row = w + (size_t)o * (2 * HD);
  int t = threadIdx.x;
  float4 a = ((const float4*)row)[t];
  ushort4 ua;
  ua.x = f2bf(a.x); ua.y = f2bf(a.y); ua.z = f2bf(a.z); ua.w = f2bf(a.w);
  *(ushort4*)(win + (size_t)gid * HD + t * 4) = ua;
}

// ---------------- precompute folded recurrent weights (fp32) --------------
// W1p[g][o][k] = Wg_rec[o,k]*g_st[k] for g in {z,r};
// Whg[o][k] = Wh_rec[o,k]*g_st[k]; Whb[o][k] = Wh_rec[o,k]*b_st[k];
// Sg[g*HD+o] = sum_k W1p[g][o][k]; Sb[g*HD+o] = sum_k Wg_rec[o,k]*b_st[k].
__global__ __launch_bounds__(256) void k_prep_rec(const float* __restrict__ wz,
    const float* __restrict__ wr, const float* __restrict__ wh,
    const float* __restrict__ g_st, const float* __restrict__ b_st,
    float* __restrict__ W1p, float* __restrict__ Whg, float* __restrict__ Whb,
    float* __restrict__ Sg, float* __restrict__ Sb) {
  int gid = blockIdx.x;
  int gate = gid >> 10, o = gid & 1023;
  const float* w = (gate == 0) ? wz : ((gate == 1) ? wr : wh);
  int t = threadIdx.x;
  float4 wv = ((const float4*)(w + (size_t)o * (2 * HD) + HD))[t];
  float4 gv = ((const float4*)g_st)[t];
  float4 bv = ((const float4*)b_st)[t];
  float4 wg, wb;
  wg.x = wv.x * gv.x; wg.y = wv.y * gv.y; wg.z = wv.z * gv.z; wg.w = wv.w * gv.w;
  wb.x = wv.x * bv.x; wb.y = wv.y * bv.y; wb.z = wv.z * bv.z; wb.w = wv.w * bv.w;
  if (gate < 2) {
    ((float4*)(W1p + ((size_t)gate << 20) + ((size_t)o << 10)))[t] = wg;
    float sg = wg.x + wg.y + wg.z + wg.w;
    float sb = wb.x + wb.y + wb.z + wb.w;
#pragma unroll
    for (int off = 32; off; off >>= 1) { sg += __shfl_down(sg, off); sb += __shfl_down(sb, off); }
    __shared__ float red[8];
    if ((t & 63) == 0) { red[t >> 6] = sg; red[4 + (t >> 6)] = sb; }
    __syncthreads();
    if (t == 0) {
      Sg[gate * HD + o] = red[0] + red[1] + red[2] + red[3];
      Sb[gate * HD + o] = red[4] + red[5] + red[6] + red[7];
    }
  } else {
    ((float4*)(Whg + ((size_t)o << 10)))[t] = wg;
    ((float4*)(Whb + ((size_t)o << 10)))[t] = wb;
  }
}

// ---------------- bf16 MFMA GEMM: C[16384,3072] = A[16384,1024] * B[3072,1024]^T
__global__ __launch_bounds__(256) void k_gemm(const u16* __restrict__ A,
    const u16* __restrict__ Bw, u16* __restrict__ C) {
  __shared__ u16 As[128 * 32];
  __shared__ u16 Bs[128 * 32];
  int tid = threadIdx.x;
  int bx = blockIdx.x % 24;       // N tile
  int by = blockIdx.x / 24;       // M tile
  int m0 = by * 128, n0 = bx * 128;
  int lane = tid & 63, wave = tid >> 6;
  int wr = wave >> 1, wc = wave & 1;
  int rl = lane & 15, kq = (lane >> 4) * 8;
  f32x4 acc[4][4] = {};
  int srow = tid >> 2, skb = (tid & 3) * 8;
  for (int k0 = 0; k0 < 1024; k0 += 32) {
    __syncthreads();
#pragma unroll
    for (int i = 0; i < 2; i++) {
      int row = srow + i * 64;
      uint4 av = *(const uint4*)(A + (size_t)(m0 + row) * 1024 + k0 + skb);
      *(uint4*)(As + row * 32 + skb) = av;
      uint4 bv = *(const uint4*)(Bw + (size_t)(n0 + row) * 1024 + k0 + skb);
      *(uint4*)(Bs + row * 32 + skb) = bv;
    }
    __syncthreads();
    bf16x8 af[4], bg[4];
#pragma unroll
    for (int mi = 0; mi < 4; mi++)
      af[mi] = *(const bf16x8*)(As + (wr * 64 + mi * 16 + rl) * 32 + kq);
#pragma unroll
    for (int ni = 0; ni < 4; ni++)
      bg[ni] = *(const bf16x8*)(Bs + (wc * 64 + ni * 16 + rl) * 32 + kq);
#pragma unroll
    for (int mi = 0; mi < 4; mi++)
#pragma unroll
      for (int ni = 0; ni < 4; ni++)
        acc[mi][ni] = __builtin_amdgcn_mfma_f32_16x16x32_bf16(af[mi], bg[ni], acc[mi][ni], 0, 0, 0);
  }
  int rowq = (lane >> 4) * 4;
#pragma unroll
  for (int mi = 0; mi < 4; mi++)
#pragma unroll
    for (int ni = 0; ni < 4; ni++)
#pragma unroll
      for (int r = 0; r < 4; r++) {
        int row = m0 + wr * 64 + mi * 16 + rowq + r;
        int col = n0 + wc * 64 + ni * 16 + rl;
        C[(size_t)row * 3072 + col] = f2bf(acc[mi][ni][r]);
      }
}

// ---------------- device-scope barrier (per-instance counters) ------------
__device__ __forceinline__ void gbar(u32* bar, int inst) {
  __syncthreads();
  __threadfence();
  if (threadIdx.x == 0) {
    u32* c = bar + inst * 16;   // 64B stride per instance
    __hip_atomic_fetch_add(c, 1u, __ATOMIC_RELAXED, __HIP_MEMORY_SCOPE_AGENT);
    while (__hip_atomic_load(c, __ATOMIC_RELAXED, __HIP_MEMORY_SCOPE_AGENT) < (u32)NBLK)
      __builtin_amdgcn_s_sleep(1);
  }
  __syncthreads();
  __threadfence();
}

// ---------------- persistent recurrence kernel ----------------------------
// 256 blocks x 512 threads. Block bl owns outputs o in [bl*4, bl*4+4) per gate.
__global__ __launch_bounds__(NTHR, 1) void k_rec(
    float* __restrict__ hglob, float* __restrict__ rglob,
    const float* __restrict__ W1p, const float* __restrict__ Whg,
    const float* __restrict__ Whb, const float* __restrict__ Sg,
    const float* __restrict__ Sb, const u16* __restrict__ gx,
    const float* __restrict__ bz, const float* __restrict__ br,
    const float* __restrict__ bh, float* __restrict__ out,
    u32* __restrict__ bar) {
  __shared__ float hs[BB * HD];
  __shared__ float rs[BB * HD];
  __shared__ float zs[32];
  __shared__ float mst[BB], rst[BB];
  const int t = threadIdx.x;
  const int bl = blockIdx.x;
  const int o0 = bl * 4;

  // phase1 thread constants: dot d1 = (gate g1, owned idx i1), 8 lanes each.
  const int d1 = t >> 3, q = t & 7;
  const int g1 = d1 >> 5, i1 = d1 & 31, b1 = i1 >> 2;
  const int o1 = o0 + (i1 & 3);
  const float4* w1row = (const float4*)(W1p + ((size_t)g1 << 20) + ((size_t)o1 << 10));
  float c_sg = 0, c_sb = 0, c_bias = 0;
  size_t gx1 = 0;
  if (q == 0) {
    c_sg = Sg[g1 * HD + o1];
    c_sb = Sb[g1 * HD + o1];
    c_bias = g1 ? br[o1] : bz[o1];
    gx1 = ((size_t)b1 * LL) * 3072 + (size_t)g1 * HD + o1;
  }
  // phase2 thread constants: dot d2 = (b2, o2), 16 lanes each.
  const int d2 = t >> 4, p = t & 15;
  const int b2 = d2 >> 2;
  const int o2 = o0 + (d2 & 3);
  const float4* wgrow = (const float4*)(Whg + ((size_t)o2 << 10));
  const float4* wbrow = (const float4*)(Whb + ((size_t)o2 << 10));
  float c_bh = 0;
  size_t gx2 = 0, outb = 0;
  int hidx = 0;
  if (p == 0) {
    c_bh = bh[o2];
    gx2 = ((size_t)b2 * LL) * 3072 + 2 * HD + o2;
    outb = ((size_t)b2 * LL) * HD + o2;
    hidx = b2 * HD + o2;
  }
  const int wvi = t >> 6, ln = t & 63;

  for (int step = 0; step < LL; step++) {
    // ---- stage h into LDS (fp32, 32KB) ----
#pragma unroll
    for (int i = 0; i < 4; i++)
      ((float4*)hs)[t + NTHR * i] = ((const float4*)hglob)[t + NTHR * i];
    __syncthreads();
    // ---- per-batch LN stats (wave wvi handles batch wvi) ----
    {
      float s = 0.f, ss = 0.f;
#pragma unroll
      for (int i = 0; i < 16; i++) {
        float v = hs[wvi * HD + ln + 64 * i];
        s += v; ss = fmaf(v, v, ss);
      }
#pragma unroll
      for (int off = 32; off; off >>= 1) { s += __shfl_xor(s, off); ss += __shfl_xor(ss, off); }
      if (ln == 0) {
        float m = s * (1.0f / HD);
        mst[wvi] = m;
        rst[wvi] = rsqrtf(ss * (1.0f / HD) - m * m + 1e-5f);
      }
    }
    __syncthreads();
    // ---- phase 1: z and r gates ----
    float gxv = 0.f;
    if (q == 0) gxv = bf2f(gx[gx1 + (size_t)step * 3072]);
    float acc = 0.f;
#pragma unroll 8
    for (int j = 0; j < 32; j++) {
      int kf = q + j * 8;
      float4 w4 = w1row[kf];
      float4 hv = ((const float4*)hs)[b1 * 256 + kf];
      acc += dot4(w4, hv);
    }
    acc += __shfl_xor(acc, 1);
    acc += __shfl_xor(acc, 2);
    acc += __shfl_xor(acc, 4);
    if (q == 0) {
      float m = mst[b1], r = rst[b1];
      float pre = fmaf(r, acc, fmaf(-m * r, c_sg, c_sb)) + gxv + c_bias;
      float sig = 1.f / (1.f + expf(-pre));
      if (g1 == 0) zs[i1] = sig;
      else rglob[b1 * HD + o1] = sig;
    }
    gbar(bar, step * 2);
    // ---- phase 2: h_cand + state update ----
#pragma unroll
    for (int i = 0; i < 4; i++)
      ((float4*)rs)[t + NTHR * i] = ((const float4*)rglob)[t + NTHR * i];
    __syncthreads();
    float gxh = 0.f;
    if (p == 0) gxh = bf2f(gx[gx2 + (size_t)step * 3072]);
    float a1 = 0.f, a2 = 0.f, a3 = 0.f;
#pragma unroll 4
    for (int j = 0; j < 16; j++) {
      int kf = p + j * 16;
      float4 wg4 = wgrow[kf];
      float4 wb4 = wbrow[kf];
      float4 hv = ((const float4*)hs)[b2 * 256 + kf];
      float4 rv = ((const float4*)rs)[b2 * 256 + kf];
      float4 rh;
      rh.x = rv.x * hv.x; rh.y = rv.y * hv.y; rh.z = rv.z * hv.z; rh.w = rv.w * hv.w;
      a1 += dot4(wg4, rh);
      a2 += dot4(wg4, rv);
      a3 += dot4(wb4, rv);
    }
#pragma unroll
    for (int off = 1; off < 16; off <<= 1) {
      a1 += __shfl_xor(a1, off);
      a2 += __shfl_xor(a2, off);
      a3 += __shfl_xor(a3, off);
    }
    if (p == 0) {
      float m = mst[b2], r = rst[b2];
      float pre = gxh + c_bh + r * a1 - m * r * a2 + a3;
      float hc = tanhf(pre);
      float z = zs[d2];
      float ho = hs[hidx];
      float hnew = fmaf(z, hc - ho, ho);
      hglob[hidx] = hnew;
      out[outb + (size_t)step * HD] = hnew;
    }
    gbar(bar, step * 2 + 1);
  }
}

__global__ __launch_bounds__(256) void k_copy(const float* __restrict__ src,
    float* __restrict__ dst, int n4) {
  int i = blockIdx.x * blockDim.x + threadIdx.x;
  if (i < n4) ((float4*)dst)[i] = ((const float4*)src)[i];
}

extern "C" void kernel_launch(void* const* d_in, const int* in_sizes, int n_in,
                              void* d_out, int out_size, void* d_ws, size_t ws_size,
                              hipStream_t stream) {
  (void)in_sizes; (void)n_in; (void)out_size; (void)ws_size;
  const float* x    = (const float*)d_in[0];
  const float* h0   = (const float*)d_in[1];
  const float* wz   = (const float*)d_in[2];
  const float* bz   = (const float*)d_in[3];
  const float* wr   = (const float*)d_in[4];
  const float* br   = (const float*)d_in[5];
  const float* wh   = (const float*)d_in[6];
  const float* bh   = (const float*)d_in[7];
  const float* g_in = (const float*)d_in[8];
  const float* b_in = (const float*)d_in[9];
  const float* g_st = (const float*)d_in[10];
  const float* b_st = (const float*)d_in[11];
  const float* g_out= (const float*)d_in[12];
  const float* b_out= (const float*)d_in[13];
  float* out = (float*)d_out;

  char* ws = (char*)d_ws;
  // region A [0,32MB): xn during frontend; folded fp32 weights afterwards
  u16*   xn   = (u16*)(ws);
  float* W1p  = (float*)(ws);                       //  8 MB (after gemm)
  float* Whg  = (float*)(ws + 8388608ull);          //  4 MB
  float* Whb  = (float*)(ws + 12582912ull);         //  4 MB
  // region B: input-side bf16 weights
  u16*   win  = (u16*)(ws + 33554432ull);           //  6 MB
  // region C: gx
  u16*   gx   = (u16*)(ws + 39845888ull);           // 96 MB -> ends 140509184
  // region D: persistent small buffers
  float* Sg   = (float*)(ws + 140509184ull);        //  8 KB
  float* Sb   = (float*)(ws + 140517376ull);        //  8 KB
  float* hgl  = (float*)(ws + 140525568ull);        // 32 KB
  float* rgl  = (float*)(ws + 140558336ull);        // 32 KB
  u32*   bar  = (u32*)(ws + 140591104ull);          // 256 KB

  k_pack_win<<<dim3(3072), dim3(256), 0, stream>>>(wz, wr, wh, win);
  k_ln_x<<<dim3(16384), dim3(256), 0, stream>>>(x, g_in, b_in, xn);
  k_gemm<<<dim3(3072), dim3(256), 0, stream>>>(xn, win, gx);
  // after gemm: xn region is dead -> write folded recurrent weights there
  k_prep_rec<<<dim3(3072), dim3(256), 0, stream>>>(wz, wr, wh, g_st, b_st,
                                                   W1p, Whg, Whb, Sg, Sb);
  hipMemsetAsync(bar, 0, 262144, stream);
  hipMemcpyAsync(hgl, h0, (size_t)BB * HD * sizeof(float),
                 hipMemcpyDeviceToDevice, stream);
  k_rec<<<dim3(NBLK), dim3(NTHR), 0, stream>>>(hgl, rgl, W1p, Whg, Whb, Sg, Sb,
                                               gx, bz, br, bh, out, bar);
  k_out_ln<<<dim3(16384), dim3(256), 0, stream>>>(out, g_out, b_out);
  k_copy<<<dim3(8), dim3(256), 0, stream>>>(hgl, out + (size_t)16384 * 1024, 2048);
}

// Round 3
// 41814.227 us; speedup vs baseline: 7.3061x; 7.3061x over previous
//
#include <hip/hip_runtime.h>
#include <stdint.h>
#include <math.h>

#define HD 1024
#define BB 8
#define LL 2048
#define NBLK 256
#define NTHR 512

typedef unsigned short u16;
typedef unsigned int u32;
typedef unsigned long long u64;

using bf16x8 = __attribute__((ext_vector_type(8))) short;
using f32x4  = __attribute__((ext_vector_type(4))) float;

__device__ __forceinline__ u16 f2bf(float f) {
  u32 x = __float_as_uint(f);
  x += 0x7fffu + ((x >> 16) & 1u);
  return (u16)(x >> 16);
}
__device__ __forceinline__ float bf2f(u16 u) {
  return __uint_as_float(((u32)u) << 16);
}
__device__ __forceinline__ float dot4(float4 a, float4 b) {
  return fmaf(a.x, b.x, fmaf(a.y, b.y, fmaf(a.z, b.z, a.w * b.w)));
}

// ---- coherent (LLC, sc1) access helpers: no cache flushes ever needed ----
__device__ __forceinline__ float2 cload2(const float* p) {
  u64 v = __hip_atomic_load((const u64*)p, __ATOMIC_RELAXED, __HIP_MEMORY_SCOPE_AGENT);
  float2 r;
  r.x = __uint_as_float((u32)v);
  r.y = __uint_as_float((u32)(v >> 32));
  return r;
}
__device__ __forceinline__ void cstore1(float* p, float a) {
  __hip_atomic_store((u32*)p, __float_as_uint(a), __ATOMIC_RELAXED, __HIP_MEMORY_SCOPE_AGENT);
}

// ---------------- input LN: x [16384,1024] f32 -> xn bf16 ----------------
__global__ __launch_bounds__(256) void k_ln_x(const float* __restrict__ x,
    const float* __restrict__ g, const float* __restrict__ b,
    u16* __restrict__ xn) {
  int row = blockIdx.x;
  int t = threadIdx.x;
  const float4* xr = (const float4*)(x + (size_t)row * HD);
  float4 v = xr[t];
  float s = v.x + v.y + v.z + v.w;
  float ss = v.x * v.x + v.y * v.y + v.z * v.z + v.w * v.w;
#pragma unroll
  for (int off = 32; off; off >>= 1) { s += __shfl_down(s, off); ss += __shfl_down(ss, off); }
  __shared__ float red[8];
  if ((t & 63) == 0) { red[t >> 6] = s; red[4 + (t >> 6)] = ss; }
  __syncthreads();
  s = red[0] + red[1] + red[2] + red[3];
  ss = red[4] + red[5] + red[6] + red[7];
  float m = s * (1.0f / HD);
  float rstd = rsqrtf(ss * (1.0f / HD) - m * m + 1e-5f);
  float4 gv = ((const float4*)g)[t];
  float4 bv = ((const float4*)b)[t];
  ushort4 o;
  o.x = f2bf((v.x - m) * rstd * gv.x + bv.x);
  o.y = f2bf((v.y - m) * rstd * gv.y + bv.y);
  o.z = f2bf((v.z - m) * rstd * gv.z + bv.z);
  o.w = f2bf((v.w - m) * rstd * gv.w + bv.w);
  *(ushort4*)(xn + (size_t)row * HD + t * 4) = o;
}

// ---------------- output LN, in place on f32 rows ----------------
__global__ __launch_bounds__(256) void k_out_ln(float* __restrict__ y,
    const float* __restrict__ g, const float* __restrict__ b) {
  int row = blockIdx.x;
  int t = threadIdx.x;
  float4* yr = (float4*)(y + (size_t)row * HD);
  float4 v = yr[t];
  float s = v.x + v.y + v.z + v.w;
  float ss = v.x * v.x + v.y * v.y + v.z * v.z + v.w * v.w;
#pragma unroll
  for (int off = 32; off; off >>= 1) { s += __shfl_down(s, off); ss += __shfl_down(ss, off); }
  __shared__ float red[8];
  if ((t & 63) == 0) { red[t >> 6] = s; red[4 + (t >> 6)] = ss; }
  __syncthreads();
  s = red[0] + red[1] + red[2] + red[3];
  ss = red[4] + red[5] + red[6] + red[7];
  float m = s * (1.0f / HD);
  float rstd = rsqrtf(ss * (1.0f / HD) - m * m + 1e-5f);
  float4 gv = ((const float4*)g)[t];
  float4 bv = ((const float4*)b)[t];
  float4 o;
  o.x = (v.x - m) * rstd * gv.x + bv.x;
  o.y = (v.y - m) * rstd * gv.y + bv.y;
  o.z = (v.z - m) * rstd * gv.z + bv.z;
  o.w = (v.w - m) * rstd * gv.w + bv.w;
  yr[t] = o;
}

// ---------------- pack input-side weights to bf16: win=[3][1024][1024] ----
__global__ __launch_bounds__(256) void k_pack_win(const float* __restrict__ wz,
    const float* __restrict__ wr, const float* __restrict__ wh,
    u16* __restrict__ win) {
  int gid = blockIdx.x;           // 0..3071
  int gate = gid >> 10, o = gid & 1023;
  const float* w = (gate == 0) ? wz : ((gate == 1) ? wr : wh);
  const float* row = w + (size_t)o * (2 * HD);
  int t = threadIdx.x;
  float4 a = ((const float4*)row)[t];
  ushort4 ua;
  ua.x = f2bf(a.x); ua.y = f2bf(a.y); ua.z = f2bf(a.z); ua.w = f2bf(a.w);
  *(ushort4*)(win + (size_t)gid * HD + t * 4) = ua;
}

// ---------------- precompute folded recurrent weights (fp32) --------------
__global__ __launch_bounds__(256) void k_prep_rec(const float* __restrict__ wz,
    const float* __restrict__ wr, const float* __restrict__ wh,
    const float* __restrict__ g_st, const float* __restrict__ b_st,
    float* __restrict__ W1p, float* __restrict__ Whg, float* __restrict__ Whb,
    float* __restrict__ Sg, float* __restrict__ Sb) {
  int gid = blockIdx.x;
  int gate = gid >> 10, o = gid & 1023;
  const float* w = (gate == 0) ? wz : ((gate == 1) ? wr : wh);
  int t = threadIdx.x;
  float4 wv = ((const float4*)(w + (size_t)o * (2 * HD) + HD))[t];
  float4 gv = ((const float4*)g_st)[t];
  float4 bv = ((const float4*)b_st)[t];
  float4 wg, wb;
  wg.x = wv.x * gv.x; wg.y = wv.y * gv.y; wg.z = wv.z * gv.z; wg.w = wv.w * gv.w;
  wb.x = wv.x * bv.x; wb.y = wv.y * bv.y; wb.z = wv.z * bv.z; wb.w = wv.w * bv.w;
  if (gate < 2) {
    ((float4*)(W1p + ((size_t)gate << 20) + ((size_t)o << 10)))[t] = wg;
    float sg = wg.x + wg.y + wg.z + wg.w;
    float sb = wb.x + wb.y + wb.z + wb.w;
#pragma unroll
    for (int off = 32; off; off >>= 1) { sg += __shfl_down(sg, off); sb += __shfl_down(sb, off); }
    __shared__ float red[8];
    if ((t & 63) == 0) { red[t >> 6] = sg; red[4 + (t >> 6)] = sb; }
    __syncthreads();
    if (t == 0) {
      Sg[gate * HD + o] = red[0] + red[1] + red[2] + red[3];
      Sb[gate * HD + o] = red[4] + red[5] + red[6] + red[7];
    }
  } else {
    ((float4*)(Whg + ((size_t)o << 10)))[t] = wg;
    ((float4*)(Whb + ((size_t)o << 10)))[t] = wb;
  }
}

// ---------------- bf16 MFMA GEMM: C[16384,3072] = A[16384,1024] * B[3072,1024]^T
__global__ __launch_bounds__(256) void k_gemm(const u16* __restrict__ A,
    const u16* __restrict__ Bw, u16* __restrict__ C) {
  __shared__ u16 As[128 * 32];
  __shared__ u16 Bs[128 * 32];
  int tid = threadIdx.x;
  int bx = blockIdx.x % 24;       // N tile
  int by = blockIdx.x / 24;       // M tile
  int m0 = by * 128, n0 = bx * 128;
  int lane = tid & 63, wave = tid >> 6;
  int wr = wave >> 1, wc = wave & 1;
  int rl = lane & 15, kq = (lane >> 4) * 8;
  f32x4 acc[4][4] = {};
  int srow = tid >> 2, skb = (tid & 3) * 8;
  for (int k0 = 0; k0 < 1024; k0 += 32) {
    __syncthreads();
#pragma unroll
    for (int i = 0; i < 2; i++) {
      int row = srow + i * 64;
      uint4 av = *(const uint4*)(A + (size_t)(m0 + row) * 1024 + k0 + skb);
      *(uint4*)(As + row * 32 + skb) = av;
      uint4 bv = *(const uint4*)(Bw + (size_t)(n0 + row) * 1024 + k0 + skb);
      *(uint4*)(Bs + row * 32 + skb) = bv;
    }
    __syncthreads();
    bf16x8 af[4], bg[4];
#pragma unroll
    for (int mi = 0; mi < 4; mi++)
      af[mi] = *(const bf16x8*)(As + (wr * 64 + mi * 16 + rl) * 32 + kq);
#pragma unroll
    for (int ni = 0; ni < 4; ni++)
      bg[ni] = *(const bf16x8*)(Bs + (wc * 64 + ni * 16 + rl) * 32 + kq);
#pragma unroll
    for (int mi = 0; mi < 4; mi++)
#pragma unroll
      for (int ni = 0; ni < 4; ni++)
        acc[mi][ni] = __builtin_amdgcn_mfma_f32_16x16x32_bf16(af[mi], bg[ni], acc[mi][ni], 0, 0, 0);
  }
  int rowq = (lane >> 4) * 4;
#pragma unroll
  for (int mi = 0; mi < 4; mi++)
#pragma unroll
    for (int ni = 0; ni < 4; ni++)
#pragma unroll
      for (int r = 0; r < 4; r++) {
        int row = m0 + wr * 64 + mi * 16 + rowq + r;
        int col = n0 + wc * 64 + ni * 16 + rl;
        C[(size_t)row * 3072 + col] = f2bf(acc[mi][ni][r]);
      }
}

// ---------------- device-scope barrier, NO cache flushes ------------------
// Producer stores are sc1 (coherent-at-LLC) relaxed atomics; vmcnt(0) makes
// them globally visible before the arrive-add (also an LLC RMW). A consumer
// observing count==NBLK therefore observes all producer data via sc1 loads.
__device__ __forceinline__ void gbar(u32* bar, int inst) {
  asm volatile("s_waitcnt vmcnt(0)" ::: "memory");
  __syncthreads();
  if (threadIdx.x == 0) {
    u32* c = bar + inst * 16;   // 64B stride per instance
    __hip_atomic_fetch_add(c, 1u, __ATOMIC_RELAXED, __HIP_MEMORY_SCOPE_AGENT);
    while (__hip_atomic_load(c, __ATOMIC_RELAXED, __HIP_MEMORY_SCOPE_AGENT) < (u32)NBLK)
      __builtin_amdgcn_s_sleep(2);
  }
  __syncthreads();
}

// ---------------- persistent recurrence kernel ----------------------------
// 256 blocks x 512 threads. Block bl owns outputs o in [bl*4, bl*4+4) per gate.
__global__ __launch_bounds__(NTHR, 1) void k_rec(
    float* __restrict__ hglob, float* __restrict__ rglob,
    const float* __restrict__ W1p, const float* __restrict__ Whg,
    const float* __restrict__ Whb, const float* __restrict__ Sg,
    const float* __restrict__ Sb, const u16* __restrict__ gx,
    const float* __restrict__ bz, const float* __restrict__ br,
    const float* __restrict__ bh, float* __restrict__ out,
    u32* __restrict__ bar) {
  __shared__ float hs[BB * HD];
  __shared__ float rs[BB * HD];
  __shared__ float zs[32];
  __shared__ float mst[BB], rst[BB];
  const int t = threadIdx.x;
  const int bl = blockIdx.x;
  const int o0 = bl * 4;

  // phase1 thread constants: dot d1 = (gate g1, owned idx i1), 8 lanes each.
  const int d1 = t >> 3, q = t & 7;
  const int g1 = d1 >> 5, i1 = d1 & 31, b1 = i1 >> 2;
  const int o1 = o0 + (i1 & 3);
  const float4* w1row = (const float4*)(W1p + ((size_t)g1 << 20) + ((size_t)o1 << 10));
  float c_sg = 0, c_sb = 0, c_bias = 0;
  size_t gx1 = 0;
  if (q == 0) {
    c_sg = Sg[g1 * HD + o1];
    c_sb = Sb[g1 * HD + o1];
    c_bias = g1 ? br[o1] : bz[o1];
    gx1 = ((size_t)b1 * LL) * 3072 + (size_t)g1 * HD + o1;
  }
  // phase2 thread constants: dot d2 = (b2, o2), 16 lanes each.
  const int d2 = t >> 4, p = t & 15;
  const int b2 = d2 >> 2;
  const int o2 = o0 + (d2 & 3);
  const float4* wgrow = (const float4*)(Whg + ((size_t)o2 << 10));
  const float4* wbrow = (const float4*)(Whb + ((size_t)o2 << 10));
  float c_bh = 0;
  size_t gx2 = 0, outb = 0;
  int hidx = 0;
  if (p == 0) {
    c_bh = bh[o2];
    gx2 = ((size_t)b2 * LL) * 3072 + 2 * HD + o2;
    outb = ((size_t)b2 * LL) * HD + o2;
    hidx = b2 * HD + o2;
  }
  const int wvi = t >> 6, ln = t & 63;

  for (int step = 0; step < LL; step++) {
    // ---- stage h into LDS via coherent 8B loads ----
#pragma unroll
    for (int i = 0; i < 8; i++) {
      int idx = t + NTHR * i;                 // 0..4095 (8B units)
      ((float2*)hs)[idx] = cload2(hglob + idx * 2);
    }
    __syncthreads();
    // ---- per-batch LN stats (wave wvi handles batch wvi) ----
    {
      float s = 0.f, ss = 0.f;
#pragma unroll
      for (int i = 0; i < 16; i++) {
        float v = hs[wvi * HD + ln + 64 * i];
        s += v; ss = fmaf(v, v, ss);
      }
#pragma unroll
      for (int off = 32; off; off >>= 1) { s += __shfl_xor(s, off); ss += __shfl_xor(ss, off); }
      if (ln == 0) {
        float m = s * (1.0f / HD);
        mst[wvi] = m;
        rst[wvi] = rsqrtf(ss * (1.0f / HD) - m * m + 1e-5f);
      }
    }
    __syncthreads();
    // ---- phase 1: z and r gates ----
    float gxv = 0.f;
    if (q == 0) gxv = bf2f(gx[gx1 + (size_t)step * 3072]);
    float acc = 0.f;
#pragma unroll 8
    for (int j = 0; j < 32; j++) {
      int kf = q + j * 8;
      float4 w4 = w1row[kf];
      float4 hv = ((const float4*)hs)[b1 * 256 + kf];
      acc += dot4(w4, hv);
    }
    acc += __shfl_xor(acc, 1);
    acc += __shfl_xor(acc, 2);
    acc += __shfl_xor(acc, 4);
    if (q == 0) {
      float m = mst[b1], r = rst[b1];
      float pre = fmaf(r, acc, fmaf(-m * r, c_sg, c_sb)) + gxv + c_bias;
      float sig = 1.f / (1.f + expf(-pre));
      if (g1 == 0) zs[i1] = sig;
      else cstore1(rglob + b1 * HD + o1, sig);
    }
    gbar(bar, step * 2);
    // ---- phase 2: h_cand + state update ----
#pragma unroll
    for (int i = 0; i < 8; i++) {
      int idx = t + NTHR * i;
      ((float2*)rs)[idx] = cload2(rglob + idx * 2);
    }
    __syncthreads();
    float gxh = 0.f;
    if (p == 0) gxh = bf2f(gx[gx2 + (size_t)step * 3072]);
    float a1 = 0.f, a2 = 0.f, a3 = 0.f;
#pragma unroll 4
    for (int j = 0; j < 16; j++) {
      int kf = p + j * 16;
      float4 wg4 = wgrow[kf];
      float4 wb4 = wbrow[kf];
      float4 hv = ((const float4*)hs)[b2 * 256 + kf];
      float4 rv = ((const float4*)rs)[b2 * 256 + kf];
      float4 rh;
      rh.x = rv.x * hv.x; rh.y = rv.y * hv.y; rh.z = rv.z * hv.z; rh.w = rv.w * hv.w;
      a1 += dot4(wg4, rh);
      a2 += dot4(wg4, rv);
      a3 += dot4(wb4, rv);
    }
#pragma unroll
    for (int off = 1; off < 16; off <<= 1) {
      a1 += __shfl_xor(a1, off);
      a2 += __shfl_xor(a2, off);
      a3 += __shfl_xor(a3, off);
    }
    if (p == 0) {
      float m = mst[b2], r = rst[b2];
      float pre = gxh + c_bh + r * a1 - m * r * a2 + a3;
      float hc = tanhf(pre);
      float z = zs[d2];
      float ho = hs[hidx];
      float hnew = fmaf(z, hc - ho, ho);
      cstore1(hglob + hidx, hnew);
      out[outb + (size_t)step * HD] = hnew;
    }
    gbar(bar, step * 2 + 1);
  }
}

__global__ __launch_bounds__(256) void k_copy(const float* __restrict__ src,
    float* __restrict__ dst, int n4) {
  int i = blockIdx.x * blockDim.x + threadIdx.x;
  if (i < n4) ((float4*)dst)[i] = ((const float4*)src)[i];
}

extern "C" void kernel_launch(void* const* d_in, const int* in_sizes, int n_in,
                              void* d_out, int out_size, void* d_ws, size_t ws_size,
                              hipStream_t stream) {
  (void)in_sizes; (void)n_in; (void)out_size; (void)ws_size;
  const float* x    = (const float*)d_in[0];
  const float* h0   = (const float*)d_in[1];
  const float* wz   = (const float*)d_in[2];
  const float* bz   = (const float*)d_in[3];
  const float* wr   = (const float*)d_in[4];
  const float* br   = (const float*)d_in[5];
  const float* wh   = (const float*)d_in[6];
  const float* bh   = (const float*)d_in[7];
  const float* g_in = (const float*)d_in[8];
  const float* b_in = (const float*)d_in[9];
  const float* g_st = (const float*)d_in[10];
  const float* b_st = (const float*)d_in[11];
  const float* g_out= (const float*)d_in[12];
  const float* b_out= (const float*)d_in[13];
  float* out = (float*)d_out;

  char* ws = (char*)d_ws;
  // region A [0,32MB): xn during frontend; folded fp32 weights afterwards
  u16*   xn   = (u16*)(ws);
  float* W1p  = (float*)(ws);                       //  8 MB (after gemm)
  float* Whg  = (float*)(ws + 8388608ull);          //  4 MB
  float* Whb  = (float*)(ws + 12582912ull);         //  4 MB
  // region B: input-side bf16 weights
  u16*   win  = (u16*)(ws + 33554432ull);           //  6 MB
  // region C: gx
  u16*   gx   = (u16*)(ws + 39845888ull);           // 96 MB -> ends 140509184
  // region D: persistent small buffers
  float* Sg   = (float*)(ws + 140509184ull);        //  8 KB
  float* Sb   = (float*)(ws + 140517376ull);        //  8 KB
  float* hgl  = (float*)(ws + 140525568ull);        // 32 KB
  float* rgl  = (float*)(ws + 140558336ull);        // 32 KB
  u32*   bar  = (u32*)(ws + 140591104ull);          // 256 KB

  k_pack_win<<<dim3(3072), dim3(256), 0, stream>>>(wz, wr, wh, win);
  k_ln_x<<<dim3(16384), dim3(256), 0, stream>>>(x, g_in, b_in, xn);
  k_gemm<<<dim3(3072), dim3(256), 0, stream>>>(xn, win, gx);
  // after gemm: xn region is dead -> write folded recurrent weights there
  k_prep_rec<<<dim3(3072), dim3(256), 0, stream>>>(wz, wr, wh, g_st, b_st,
                                                   W1p, Whg, Whb, Sg, Sb);
  hipMemsetAsync(bar, 0, 262144, stream);
  hipMemcpyAsync(hgl, h0, (size_t)BB * HD * sizeof(float),
                 hipMemcpyDeviceToDevice, stream);
  k_rec<<<dim3(NBLK), dim3(NTHR), 0, stream>>>(hgl, rgl, W1p, Whg, Whb, Sg, Sb,
                                               gx, bz, br, bh, out, bar);
  k_out_ln<<<dim3(16384), dim3(256), 0, stream>>>(out, g_out, b_out);
  k_copy<<<dim3(8), dim3(256), 0, stream>>>(hgl, out + (size_t)16384 * 1024, 2048);
}

// Round 5
// 20989.833 us; speedup vs baseline: 14.5546x; 1.9921x over previous
//
#include <hip/hip_runtime.h>
#include <stdint.h>
#include <math.h>

#define HD 1024
#define BB 8
#define LL 2048
#define NBLK 256
#define NTHR 512

typedef unsigned short u16;
typedef unsigned int u32;
typedef unsigned long long u64;

using bf16x8 = __attribute__((ext_vector_type(8))) short;
using f32x4  = __attribute__((ext_vector_type(4))) float;

__device__ __forceinline__ u16 f2bf(float f) {
  u32 x = __float_as_uint(f);
  x += 0x7fffu + ((x >> 16) & 1u);
  return (u16)(x >> 16);
}
__device__ __forceinline__ float bf2f(u16 u) {
  return __uint_as_float(((u32)u) << 16);
}
__device__ __forceinline__ float dot4(float4 a, float4 b) {
  return fmaf(a.x, b.x, fmaf(a.y, b.y, fmaf(a.z, b.z, a.w * b.w)));
}
__device__ __forceinline__ float sigmoidf(float x) { return 1.f / (1.f + expf(-x)); }

// ---- coherent LLC accesses via relaxed agent atomics (compiler-tracked) ----
__device__ __forceinline__ float2 cload2(const u64* p) {
  u64 v = __hip_atomic_load(p, __ATOMIC_RELAXED, __HIP_MEMORY_SCOPE_AGENT);
  float2 r;
  r.x = __uint_as_float((u32)v);
  r.y = __uint_as_float((u32)(v >> 32));
  return r;
}
__device__ __forceinline__ void cstore1(float* p, float a) {
  __hip_atomic_store((u32*)p, __float_as_uint(a), __ATOMIC_RELAXED, __HIP_MEMORY_SCOPE_AGENT);
}

// ---- tree barrier: 16 groups x 16 blocks, monotonic counters, 4 instances ----
// layout (u32 idx): group line (inst,g) at (inst*16+g)*16 ; root(inst) at 1024+inst*16
__device__ __forceinline__ void bar_arrive(u32* bar, int n, int grp) {
  int inst = n & 3;
  u32 tgt = (u32)((n >> 2) + 1) * 16u;
  u32 old = __hip_atomic_fetch_add(&bar[(inst * 16 + grp) * 16], 1u,
                                   __ATOMIC_RELAXED, __HIP_MEMORY_SCOPE_AGENT);
  if (old == tgt - 1u)
    __hip_atomic_fetch_add(&bar[1024 + inst * 16], 1u,
                           __ATOMIC_RELAXED, __HIP_MEMORY_SCOPE_AGENT);
}
__device__ __forceinline__ void bar_wait(u32* bar, int n) {
  int inst = n & 3;
  u32 tgt = (u32)((n >> 2) + 1) * 16u;
  while (__hip_atomic_load(&bar[1024 + inst * 16],
                           __ATOMIC_RELAXED, __HIP_MEMORY_SCOPE_AGENT) < tgt)
    __builtin_amdgcn_s_sleep(1);
}

// ---------------- input LN: x [16384,1024] f32 -> xn bf16 ----------------
__global__ __launch_bounds__(256) void k_ln_x(const float* __restrict__ x,
    const float* __restrict__ g, const float* __restrict__ b,
    u16* __restrict__ xn) {
  int row = blockIdx.x;
  int t = threadIdx.x;
  const float4* xr = (const float4*)(x + (size_t)row * HD);
  float4 v = xr[t];
  float s = v.x + v.y + v.z + v.w;
  float ss = v.x * v.x + v.y * v.y + v.z * v.z + v.w * v.w;
#pragma unroll
  for (int off = 32; off; off >>= 1) { s += __shfl_down(s, off); ss += __shfl_down(ss, off); }
  __shared__ float red[8];
  if ((t & 63) == 0) { red[t >> 6] = s; red[4 + (t >> 6)] = ss; }
  __syncthreads();
  s = red[0] + red[1] + red[2] + red[3];
  ss = red[4] + red[5] + red[6] + red[7];
  float m = s * (1.0f / HD);
  float rstd = rsqrtf(ss * (1.0f / HD) - m * m + 1e-5f);
  float4 gv = ((const float4*)g)[t];
  float4 bv = ((const float4*)b)[t];
  ushort4 o;
  o.x = f2bf((v.x - m) * rstd * gv.x + bv.x);
  o.y = f2bf((v.y - m) * rstd * gv.y + bv.y);
  o.z = f2bf((v.z - m) * rstd * gv.z + bv.z);
  o.w = f2bf((v.w - m) * rstd * gv.w + bv.w);
  *(ushort4*)(xn + (size_t)row * HD + t * 4) = o;
}

// ---------------- output LN, in place on f32 rows ----------------
__global__ __launch_bounds__(256) void k_out_ln(float* __restrict__ y,
    const float* __restrict__ g, const float* __restrict__ b) {
  int row = blockIdx.x;
  int t = threadIdx.x;
  float4* yr = (float4*)(y + (size_t)row * HD);
  float4 v = yr[t];
  float s = v.x + v.y + v.z + v.w;
  float ss = v.x * v.x + v.y * v.y + v.z * v.z + v.w * v.w;
#pragma unroll
  for (int off = 32; off; off >>= 1) { s += __shfl_down(s, off); ss += __shfl_down(ss, off); }
  __shared__ float red[8];
  if ((t & 63) == 0) { red[t >> 6] = s; red[4 + (t >> 6)] = ss; }
  __syncthreads();
  s = red[0] + red[1] + red[2] + red[3];
  ss = red[4] + red[5] + red[6] + red[7];
  float m = s * (1.0f / HD);
  float rstd = rsqrtf(ss * (1.0f / HD) - m * m + 1e-5f);
  float4 gv = ((const float4*)g)[t];
  float4 bv = ((const float4*)b)[t];
  float4 o;
  o.x = (v.x - m) * rstd * gv.x + bv.x;
  o.y = (v.y - m) * rstd * gv.y + bv.y;
  o.z = (v.z - m) * rstd * gv.z + bv.z;
  o.w = (v.w - m) * rstd * gv.w + bv.w;
  yr[t] = o;
}

// ---------------- pack input-side weights to bf16: win=[3][1024][1024] ----
__global__ __launch_bounds__(256) void k_pack_win(const float* __restrict__ wz,
    const float* __restrict__ wr, const float* __restrict__ wh,
    u16* __restrict__ win) {
  int gid = blockIdx.x;           // 0..3071
  int gate = gid >> 10, o = gid & 1023;
  const float* w = (gate == 0) ? wz : ((gate == 1) ? wr : wh);
  const float* row = w + (size_t)o * (2 * HD);
  int t = threadIdx.x;
  float4 a = ((const float4*)row)[t];
  ushort4 ua;
  ua.x = f2bf(a.x); ua.y = f2bf(a.y); ua.z = f2bf(a.z); ua.w = f2bf(a.w);
  *(ushort4*)(win + (size_t)gid * HD + t * 4) = ua;
}

// ---------------- precompute folded recurrent weights (fp32) --------------
__global__ __launch_bounds__(256) void k_prep_rec(const float* __restrict__ wz,
    const float* __restrict__ wr, const float* __restrict__ wh,
    const float* __restrict__ g_st, const float* __restrict__ b_st,
    float* __restrict__ W1p, float* __restrict__ Whg, float* __restrict__ Whb,
    float* __restrict__ Sg, float* __restrict__ Sb) {
  int gid = blockIdx.x;
  int gate = gid >> 10, o = gid & 1023;
  const float* w = (gate == 0) ? wz : ((gate == 1) ? wr : wh);
  int t = threadIdx.x;
  float4 wv = ((const float4*)(w + (size_t)o * (2 * HD) + HD))[t];
  float4 gv = ((const float4*)g_st)[t];
  float4 bv = ((const float4*)b_st)[t];
  float4 wg, wb;
  wg.x = wv.x * gv.x; wg.y = wv.y * gv.y; wg.z = wv.z * gv.z; wg.w = wv.w * gv.w;
  wb.x = wv.x * bv.x; wb.y = wv.y * bv.y; wb.z = wv.z * bv.z; wb.w = wv.w * bv.w;
  if (gate < 2) {
    ((float4*)(W1p + ((size_t)gate << 20) + ((size_t)o << 10)))[t] = wg;
    float sg = wg.x + wg.y + wg.z + wg.w;
    float sb = wb.x + wb.y + wb.z + wb.w;
#pragma unroll
    for (int off = 32; off; off >>= 1) { sg += __shfl_down(sg, off); sb += __shfl_down(sb, off); }
    __shared__ float red[8];
    if ((t & 63) == 0) { red[t >> 6] = sg; red[4 + (t >> 6)] = sb; }
    __syncthreads();
    if (t == 0) {
      Sg[gate * HD + o] = red[0] + red[1] + red[2] + red[3];
      Sb[gate * HD + o] = red[4] + red[5] + red[6] + red[7];
    }
  } else {
    ((float4*)(Whg + ((size_t)o << 10)))[t] = wg;
    ((float4*)(Whb + ((size_t)o << 10)))[t] = wb;
  }
}

// ---------------- bf16 MFMA GEMM: C[16384,3072] = A[16384,1024] * B[3072,1024]^T
__global__ __launch_bounds__(256) void k_gemm(const u16* __restrict__ A,
    const u16* __restrict__ Bw, u16* __restrict__ C) {
  __shared__ u16 As[128 * 32];
  __shared__ u16 Bs[128 * 32];
  int tid = threadIdx.x;
  int bx = blockIdx.x % 24;       // N tile
  int by = blockIdx.x / 24;       // M tile
  int m0 = by * 128, n0 = bx * 128;
  int lane = tid & 63, wave = tid >> 6;
  int wr = wave >> 1, wc = wave & 1;
  int rl = lane & 15, kq = (lane >> 4) * 8;
  f32x4 acc[4][4] = {};
  int srow = tid >> 2, skb = (tid & 3) * 8;
  for (int k0 = 0; k0 < 1024; k0 += 32) {
    __syncthreads();
#pragma unroll
    for (int i = 0; i < 2; i++) {
      int row = srow + i * 64;
      uint4 av = *(const uint4*)(A + (size_t)(m0 + row) * 1024 + k0 + skb);
      *(uint4*)(As + row * 32 + skb) = av;
      uint4 bv = *(const uint4*)(Bw + (size_t)(n0 + row) * 1024 + k0 + skb);
      *(uint4*)(Bs + row * 32 + skb) = bv;
    }
    __syncthreads();
    bf16x8 af[4], bg[4];
#pragma unroll
    for (int mi = 0; mi < 4; mi++)
      af[mi] = *(const bf16x8*)(As + (wr * 64 + mi * 16 + rl) * 32 + kq);
#pragma unroll
    for (int ni = 0; ni < 4; ni++)
      bg[ni] = *(const bf16x8*)(Bs + (wc * 64 + ni * 16 + rl) * 32 + kq);
#pragma unroll
    for (int mi = 0; mi < 4; mi++)
#pragma unroll
      for (int ni = 0; ni < 4; ni++)
        acc[mi][ni] = __builtin_amdgcn_mfma_f32_16x16x32_bf16(af[mi], bg[ni], acc[mi][ni], 0, 0, 0);
  }
  int rowq = (lane >> 4) * 4;
#pragma unroll
  for (int mi = 0; mi < 4; mi++)
#pragma unroll
    for (int ni = 0; ni < 4; ni++)
#pragma unroll
      for (int r = 0; r < 4; r++) {
        int row = m0 + wr * 64 + mi * 16 + rowq + r;
        int col = n0 + wc * 64 + ni * 16 + rl;
        C[(size_t)row * 3072 + col] = f2bf(acc[mi][ni][r]);
      }
}

// ---------------- persistent recurrence kernel ----------------------------
// 256 blocks x 512 threads; block bl owns outputs [bl*4, bl*4+4) per gate.
// Wave w inside a block owns batch w exclusively (stage/LN/dots all wave-local).
__global__ __launch_bounds__(NTHR, 1) void k_rec(
    float* __restrict__ hglob, float* __restrict__ rglob,
    const float* __restrict__ W1p, const float* __restrict__ Whg,
    const float* __restrict__ Whb, const float* __restrict__ Sg,
    const float* __restrict__ Sb, const u16* __restrict__ gx,
    const float* __restrict__ bz, const float* __restrict__ br,
    const float* __restrict__ bh, float* __restrict__ out,
    u32* __restrict__ bar) {
  __shared__ float hs[BB * HD];
  __shared__ float rs[BB * HD];
  const int t = threadIdx.x;
  const int bl = blockIdx.x;
  const int grp = bl >> 4;
  const int o0 = bl * 4;
  const int w = t >> 6, ln = t & 63;
  const int p = t & 15, oi = (ln >> 4) & 3;
  const int o = o0 + oi;

  const float4* wZ = (const float4*)(W1p + ((size_t)o << 10));
  const float4* wR = (const float4*)(W1p + (1u << 20) + ((size_t)o << 10));
  const float4* wG = (const float4*)(Whg + ((size_t)o << 10));
  const float4* wB = (const float4*)(Whb + ((size_t)o << 10));
  const float sgZ = Sg[o],      sbZ = Sb[o],      biZ = bz[o];
  const float sgR = Sg[HD + o], sbR = Sb[HD + o], biR = br[o];
  const float bhc = bh[o];
  const u16* gxZ = gx + ((size_t)w * LL) * 3072 + o;
  const u16* gxR = gxZ + HD;
  const u16* gxH = gxZ + 2 * HD;
  const int hidx = w * HD + o;
  const size_t outb = ((size_t)w * LL) * HD + o;
  const float4* hv4 = (const float4*)(hs + w * HD);
  const float4* rv4 = (const float4*)(rs + w * HD);

  for (int step = 0; step < LL; step++) {
    // ---- stage h[batch w] -> LDS (wave-local, coherent loads) + LN stats ----
    float m, rstd, gxvR, gxvZ, gxvH;
    {
      float2 h2[8];
      const u64* src = (const u64*)(hglob + (size_t)w * HD) + ln;
#pragma unroll
      for (int i = 0; i < 8; i++) h2[i] = cload2(src + 64 * i);
      gxvR = bf2f(gxR[(size_t)step * 3072]);
      gxvZ = bf2f(gxZ[(size_t)step * 3072]);
      gxvH = bf2f(gxH[(size_t)step * 3072]);
      float2* hw = (float2*)(hs + w * HD) + ln;
      float s = 0.f, ss = 0.f;
#pragma unroll
      for (int i = 0; i < 8; i++) {
        hw[64 * i] = h2[i];
        s += h2[i].x + h2[i].y;
        ss = fmaf(h2[i].x, h2[i].x, fmaf(h2[i].y, h2[i].y, ss));
      }
#pragma unroll
      for (int mk = 1; mk < 64; mk <<= 1) { s += __shfl_xor(s, mk); ss += __shfl_xor(ss, mk); }
      m = s * (1.0f / HD);
      rstd = rsqrtf(ss * (1.0f / HD) - m * m + 1e-5f);
    }
    // ---- r gate first: compute, publish, arrive ----
    float accR = 0.f;
#pragma unroll 4
    for (int j = 0; j < 16; j++) {
      int kf = p + j * 16;
      accR += dot4(wR[kf], hv4[kf]);
    }
    accR += __shfl_xor(accR, 1);
    accR += __shfl_xor(accR, 2);
    accR += __shfl_xor(accR, 4);
    accR += __shfl_xor(accR, 8);
    if (p == 0) {
      float pre = fmaf(rstd, accR, fmaf(-m * rstd, sgR, sbR)) + gxvR + biR;
      cstore1(rglob + hidx, sigmoidf(pre));
    }
    __syncthreads();            // implies vmcnt(0)+lgkmcnt(0) drain
    if (t == 0) bar_arrive(bar, 2 * step, grp);
    // ---- z gate overlapped with barrier-1 wait ----
    float accZ = 0.f;
#pragma unroll 4
    for (int j = 0; j < 16; j++) {
      int kf = p + j * 16;
      accZ += dot4(wZ[kf], hv4[kf]);
    }
    accZ += __shfl_xor(accZ, 1);
    accZ += __shfl_xor(accZ, 2);
    accZ += __shfl_xor(accZ, 4);
    accZ += __shfl_xor(accZ, 8);
    float zreg = 0.f;
    if (p == 0) {
      float pre = fmaf(rstd, accZ, fmaf(-m * rstd, sgZ, sbZ)) + gxvZ + biZ;
      zreg = sigmoidf(pre);
    }
    if (t == 0) bar_wait(bar, 2 * step);
    __syncthreads();
    // ---- stage r[batch w] -> LDS (wave-local, coherent loads) ----
    {
      float2 r2[8];
      const u64* src = (const u64*)(rglob + (size_t)w * HD) + ln;
#pragma unroll
      for (int i = 0; i < 8; i++) r2[i] = cload2(src + 64 * i);
      float2* rw = (float2*)(rs + w * HD) + ln;
#pragma unroll
      for (int i = 0; i < 8; i++) rw[64 * i] = r2[i];
    }
    // ---- phase 2: h_cand + state update ----
    float a1s = 0.f, a2s = 0.f, a3s = 0.f;
#pragma unroll 2
    for (int j = 0; j < 16; j++) {
      int kf = p + j * 16;
      float4 wg4 = wG[kf];
      float4 wb4 = wB[kf];
      float4 hv = hv4[kf];
      float4 rv = rv4[kf];
      float4 rh;
      rh.x = rv.x * hv.x; rh.y = rv.y * hv.y; rh.z = rv.z * hv.z; rh.w = rv.w * hv.w;
      a1s += dot4(wg4, rh);
      a2s += dot4(wg4, rv);
      a3s += dot4(wb4, rv);
    }
#pragma unroll
    for (int mk = 1; mk < 16; mk <<= 1) {
      a1s += __shfl_xor(a1s, mk);
      a2s += __shfl_xor(a2s, mk);
      a3s += __shfl_xor(a3s, mk);
    }
    float hnew = 0.f;
    if (p == 0) {
      float pre = gxvH + bhc + rstd * a1s - m * rstd * a2s + a3s;
      float hc = tanhf(pre);
      float ho = hs[hidx];
      hnew = fmaf(zreg, hc - ho, ho);
      cstore1(hglob + hidx, hnew);
    }
    __syncthreads();            // drains the cstore1 before arrive
    if (t == 0) bar_arrive(bar, 2 * step + 1, grp);
    if (p == 0) out[outb + (size_t)step * HD] = hnew;
    if (t == 0) bar_wait(bar, 2 * step + 1);
    __syncthreads();
  }
}

__global__ __launch_bounds__(256) void k_copy(const float* __restrict__ src,
    float* __restrict__ dst, int n4) {
  int i = blockIdx.x * blockDim.x + threadIdx.x;
  if (i < n4) ((float4*)dst)[i] = ((const float4*)src)[i];
}

extern "C" void kernel_launch(void* const* d_in, const int* in_sizes, int n_in,
                              void* d_out, int out_size, void* d_ws, size_t ws_size,
                              hipStream_t stream) {
  (void)in_sizes; (void)n_in; (void)out_size; (void)ws_size;
  const float* x    = (const float*)d_in[0];
  const float* h0   = (const float*)d_in[1];
  const float* wz   = (const float*)d_in[2];
  const float* bz   = (const float*)d_in[3];
  const float* wr   = (const float*)d_in[4];
  const float* br   = (const float*)d_in[5];
  const float* wh   = (const float*)d_in[6];
  const float* bh   = (const float*)d_in[7];
  const float* g_in = (const float*)d_in[8];
  const float* b_in = (const float*)d_in[9];
  const float* g_st = (const float*)d_in[10];
  const float* b_st = (const float*)d_in[11];
  const float* g_out= (const float*)d_in[12];
  const float* b_out= (const float*)d_in[13];
  float* out = (float*)d_out;

  char* ws = (char*)d_ws;
  // region A [0,32MB): xn during frontend; folded fp32 weights afterwards
  u16*   xn   = (u16*)(ws);
  float* W1p  = (float*)(ws);                       //  8 MB (after gemm)
  float* Whg  = (float*)(ws + 8388608ull);          //  4 MB
  float* Whb  = (float*)(ws + 12582912ull);         //  4 MB
  // region B: input-side bf16 weights
  u16*   win  = (u16*)(ws + 33554432ull);           //  6 MB
  // region C: gx
  u16*   gx   = (u16*)(ws + 39845888ull);           // 96 MB -> ends 140509184
  // region D: persistent small buffers
  float* Sg   = (float*)(ws + 140509184ull);        //  8 KB
  float* Sb   = (float*)(ws + 140517376ull);        //  8 KB
  float* hgl  = (float*)(ws + 140525568ull);        // 32 KB
  float* rgl  = (float*)(ws + 140558336ull);        // 32 KB
  u32*   bar  = (u32*)(ws + 140591104ull);          //  8 KB barrier counters

  k_pack_win<<<dim3(3072), dim3(256), 0, stream>>>(wz, wr, wh, win);
  k_ln_x<<<dim3(16384), dim3(256), 0, stream>>>(x, g_in, b_in, xn);
  k_gemm<<<dim3(3072), dim3(256), 0, stream>>>(xn, win, gx);
  // after gemm: xn region is dead -> write folded recurrent weights there
  k_prep_rec<<<dim3(3072), dim3(256), 0, stream>>>(wz, wr, wh, g_st, b_st,
                                                   W1p, Whg, Whb, Sg, Sb);
  hipMemsetAsync(bar, 0, 8192, stream);
  hipMemcpyAsync(hgl, h0, (size_t)BB * HD * sizeof(float),
                 hipMemcpyDeviceToDevice, stream);
  k_rec<<<dim3(NBLK), dim3(NTHR), 0, stream>>>(hgl, rgl, W1p, Whg, Whb, Sg, Sb,
                                               gx, bz, br, bh, out, bar);
  k_out_ln<<<dim3(16384), dim3(256), 0, stream>>>(out, g_out, b_out);
  k_copy<<<dim3(8), dim3(256), 0, stream>>>(hgl, out + (size_t)16384 * 1024, 2048);
}